// Round 14
// baseline (1394.704 us; speedup 1.0000x reference)
//
#include <hip/hip_runtime.h>

#define HID 768
#define WPB 64     // words per tile (M = 256 rows)
#define MROWS 256
#define NCH 12     // K-tiles of 64
#define NSTRIP 3   // 3 col-strips x 256 cols

typedef __attribute__((ext_vector_type(4))) float f32x4;
typedef __attribute__((ext_vector_type(8))) short s16x8;
typedef __attribute__((ext_vector_type(4))) short s16x4;

__device__ inline short f2bf(float f) {
  unsigned u = __builtin_bit_cast(unsigned, f);
  u = (u + 0x7fffu + ((u >> 16) & 1u)) >> 16;
  return (short)(unsigned short)u;
}
__device__ inline float fast_tanh(float v) {
  float e = exp2f(v * 2.885390081777927f);   // e^{2v}
  return 1.0f - 2.0f * __builtin_amdgcn_rcpf(e + 1.0f);
}
__device__ inline s16x8 pack8(f32x4 f0, f32x4 f1) {
  s16x8 p;
  p[0]=f2bf(f0[0]); p[1]=f2bf(f0[1]); p[2]=f2bf(f0[2]); p[3]=f2bf(f0[3]);
  p[4]=f2bf(f1[0]); p[5]=f2bf(f1[1]); p[6]=f2bf(f1[2]); p[7]=f2bf(f1[3]);
  return p;
}
__device__ inline s16x4 pack4(f32x4 f) {
  s16x4 p;
  p[0]=f2bf(f[0]); p[1]=f2bf(f[1]); p[2]=f2bf(f[2]); p[3]=f2bf(f[3]);
  return p;
}

// ---- pre-pass: W fp32 -> bf16 in MFMA FRAGMENT ORDER (verified r7-r13) ----
__global__ void wconv_kernel(const float* __restrict__ W, short* __restrict__ Wb, int n64) {
  int gid = blockIdx.x * blockDim.x + threadIdx.x;
  if (gid >= n64) return;                  // 24*48*64 = 73728
  int lane = gid & 63;
  int frag = gid >> 6;
  int kc = frag / 48;
  int t  = frag - kc * 48;
  int col = t * 16 + (lane & 15);
  int k0  = kc * 32 + (lane >> 4) * 8;
  const float* src = W + (size_t)col * HID + k0;
  f32x4 f0 = *(const f32x4*)src;
  f32x4 f1 = *(const f32x4*)(src + 4);
  *(s16x8*)(Wb + (size_t)gid * 8) = pack8(f0, f1);
}

// ==== main: 256x256-strip tiles, 8 waves, m201-style 4-sub-phase K schedule ====
__global__ __launch_bounds__(512, 2) void gemm_8ph(
    const float* __restrict__ x, const short* __restrict__ Wb,
    const float* __restrict__ bias, const float* __restrict__ scw,
    const int* __restrict__ mapping, float* __restrict__ out,
    int num_words, float* __restrict__ s_glob, int* __restrict__ cnt, int swz)
{
  __shared__ short Abuf[2 * 16384];        // 64 KB: A bf16, verified swizzle, dbuf
  __shared__ short Bbuf[2 * 16384];        // 64 KB: B fragments, linear, dbuf
  __shared__ float s_lds[MROWS];
  __shared__ int lastflag;

  const int tid = threadIdx.x;
  int tile, strip;
  if (swz) {                               // strip-siblings differ by 8 in blockIdx
    int q = blockIdx.x / 24;               // -> same XCD -> shared A in L2 (r13 ✓)
    int rr = blockIdx.x - q * 24;
    tile = q * 8 + (rr & 7);
    strip = rr >> 3;
  } else {
    tile = blockIdx.x / NSTRIP;
    strip = blockIdx.x - tile * NSTRIP;
  }
  const int w0 = tile * WPB;
  const int wlast = min(w0 + WPB - 1, num_words - 1);
  const int r0 = mapping[2 * w0];
  const int r1 = mapping[2 * wlast + 1];
  const int nrows = min(r1 - r0, MROWS);

  // A staging map (r9/r13-verified, 0 conflicts)
  const int arow = tid >> 4;               // 0..31
  const int aslot = tid & 15;
  const float* xs = x + (size_t)(r0 + arow) * HID + aslot * 4;
  const int lofs = arow * 128 + ((aslot * 8) ^ ((arow & 7) << 4));
  bool rok[8];
  #pragma unroll
  for (int i = 0; i < 8; ++i) rok[i] = (arow + 32 * i) < nrows;

  if (tid < MROWS) s_lds[tid] = 0.0f;

  // MFMA geometry: 8 waves = 2M x 4N; wave-tile 128 x 64
  const int lane = tid & 63;
  const int wave = tid >> 6;
  const int mw = wave >> 2;
  const int nw = wave & 3;
  const int l15 = lane & 15;
  const int lk  = lane >> 4;
  const int col0 = (lk * 16) ^ ((l15 & 7) << 4);
  const int col1 = col0 ^ 64;

  f32x4 acc[8][4];
  #pragma unroll
  for (int m = 0; m < 8; ++m)
    #pragma unroll
    for (int n = 0; n < 4; ++n) acc[m][n] = (f32x4){0,0,0,0};

  f32x4 pa[8];
  s16x8 pbz[4];
  s16x8 af[8];

  #define A_ISS(H, KT) do { _Pragma("unroll") for (int i_ = 0; i_ < 4; ++i_) { \
      int x_ = (H) * 4 + i_; \
      pa[x_] = rok[x_] ? *(const f32x4*)(xs + (size_t)(32 * x_) * HID + (KT) * 64) \
                       : (f32x4){0,0,0,0}; } } while(0)

  #define A_WRT(H, S) do { _Pragma("unroll") for (int i_ = 0; i_ < 4; ++i_) { \
      int x_ = (H) * 4 + i_; \
      *(s16x4*)((char*)Abuf + (S) * 32768 + lofs + x_ * 4096) = pack4(pa[x_]); } } while(0)

  #define B_ISS(KT) do { _Pragma("unroll") for (int j_ = 0; j_ < 4; ++j_) { \
      int s_ = tid + j_ * 512; \
      int kk_ = s_ >> 10, t_ = (s_ >> 6) & 15, ln_ = s_ & 63; \
      pbz[j_] = *(const s16x8*)(Wb + \
          ((size_t)(((KT) * 2 + kk_) * 48 + strip * 16 + t_)) * 512 + ln_ * 8); } } while(0)

  #define B_WRT(H, S) do { _Pragma("unroll") for (int j_ = 0; j_ < 2; ++j_) { \
      int jj_ = (H) * 2 + j_; \
      *(s16x8*)(Bbuf + (S) * 16384 + (size_t)(tid + jj_ * 512) * 8) = pbz[jj_]; } } while(0)

  #define LDA(C, COL) do { \
      const char* ab_ = (const char*)Abuf + (C) * 32768 + (mw * 128 + l15) * 128 + (COL); \
      _Pragma("unroll") for (int m_ = 0; m_ < 8; ++m_) \
        af[m_] = *(const s16x8*)(ab_ + m_ * 2048); } while(0)

  #define QMM(C, KK, N0, N1) do { \
      s16x8 b0_ = *(const s16x8*)(Bbuf + (C) * 16384 + (KK) * 8192 + (nw * 4 + (N0)) * 512 + lane * 8); \
      s16x8 b1_ = *(const s16x8*)(Bbuf + (C) * 16384 + (KK) * 8192 + (nw * 4 + (N1)) * 512 + lane * 8); \
      __builtin_amdgcn_s_setprio(1); \
      _Pragma("unroll") for (int m_ = 0; m_ < 8; ++m_) { \
        acc[m_][N0] = __builtin_amdgcn_mfma_f32_16x16x32_bf16(af[m_], b0_, acc[m_][N0], 0,0,0); \
        acc[m_][N1] = __builtin_amdgcn_mfma_f32_16x16x32_bf16(af[m_], b1_, acc[m_][N1], 0,0,0); } \
      __builtin_amdgcn_s_setprio(0); } while(0)

  #define BAR() __builtin_amdgcn_s_barrier()
  #define LGKM0() asm volatile("s_waitcnt lgkmcnt(0)" ::: "memory")

  // ---- prologue: tile 0 fully staged into buf0; A(t1) half1 in flight ----
  A_ISS(0, 0); A_ISS(1, 0); B_ISS(0);
  A_WRT(0, 0); A_WRT(1, 0); B_WRT(0, 0); B_WRT(1, 0);
  A_ISS(0, 1);
  LGKM0(); BAR();

  // ---- K loop: 4 sub-phases per K-tile; loads span >=2 phases; no vmcnt(0) ----
  #pragma unroll 1
  for (int kt = 0; kt < NCH; ++kt) {
    const int c = kt & 1, sb = c ^ 1;
    const bool nx1 = (kt + 1 < NCH), nx2 = (kt + 2 < NCH);
    // P0: issue next-tile B + A-half2; compute kk0 x n{0,1}
    if (nx1) { B_ISS(kt + 1); A_ISS(1, kt + 1); }
    LDA(c, col0);
    QMM(c, 0, 0, 1);
    BAR();
    // P1: compute kk0 x n{2,3} (reuse af)
    QMM(c, 0, 2, 3);
    BAR();
    // P2: write half1 of next tile; compute kk1 x n{0,1}
    if (nx1) { A_WRT(0, sb); B_WRT(0, sb); }
    LDA(c, col1);
    QMM(c, 1, 0, 1);
    BAR();
    // P3: issue A(t+2) half1; write half2; compute kk1 x n{2,3}
    if (nx2) A_ISS(0, kt + 2);
    if (nx1) { A_WRT(1, sb); B_WRT(1, sb); }
    QMM(c, 1, 2, 3);
    LGKM0();
    __builtin_amdgcn_sched_barrier(0);
    BAR();
  }

  // --- tanh + scorer dot (wave's 64 cols of this strip) -> s_lds ---
  float wv[4], bv[4];
  #pragma unroll
  for (int n = 0; n < 4; ++n) {
    int col = strip * 256 + nw * 64 + n * 16 + l15;
    wv[n] = scw[col];
    bv[n] = bias[col];
  }
  #pragma unroll
  for (int m = 0; m < 8; ++m) {
    #pragma unroll
    for (int r = 0; r < 4; ++r) {
      float v = 0.0f;
      #pragma unroll
      for (int n = 0; n < 4; ++n)
        v += fast_tanh(acc[m][n][r] + bv[n]) * wv[n];
      v += __shfl_xor(v, 1);
      v += __shfl_xor(v, 2);
      v += __shfl_xor(v, 4);
      v += __shfl_xor(v, 8);
      if (l15 == 0) atomicAdd(&s_lds[mw * 128 + m * 16 + lk * 4 + r], v);
    }
  }
  __syncthreads();

  // publish strip partials, counter handshake (r11/r13-verified)
  if (tid < nrows) atomicAdd(&s_glob[r0 + tid], s_lds[tid]);
  __syncthreads();
  if (tid == 0) {
    __threadfence();
    int old = atomicAdd(&cnt[tile], 1);
    lastflag = (old == NSTRIP - 1) ? 1 : 0;
  }
  __syncthreads();
  if (!lastflag) return;
  __threadfence();

  if (tid < MROWS)
    s_lds[tid] = (tid < nrows)
        ? __hip_atomic_load(&s_glob[r0 + tid], __ATOMIC_RELAXED, __HIP_MEMORY_SCOPE_AGENT)
        : 0.0f;
  __syncthreads();

  // --- per-word softmax + weighted sum (x L2/L3-warm), 8 waves x 8 words ---
  const float LOG2E = 1.4426950408889634f;
  for (int wi = wave; wi < WPB; wi += 8) {
    int gw = w0 + wi;
    if (gw >= num_words) break;
    int grs = mapping[2 * gw];
    int lrs = grs - r0;
    int cnt_ = min(mapping[2 * gw + 1] - r0, nrows) - lrs;
    float mmax = -3.0e38f;
    for (int i = 0; i < cnt_; ++i) mmax = fmaxf(mmax, s_lds[lrs + i]);
    float denom = 0.0f;
    for (int i = 0; i < cnt_; ++i) denom += exp2f((s_lds[lrs + i] - mmax) * LOG2E);
    float rden = (denom > 0.0f) ? (1.0f / denom) : 0.0f;
    float pbuf[8];
    #pragma unroll
    for (int i = 0; i < 8; ++i)
      pbuf[i] = (i < cnt_) ? exp2f((s_lds[lrs + i] - mmax) * LOG2E) * rden : 0.0f;
    #pragma unroll
    for (int j = 0; j < 3; ++j) {
      int col = j * 256 + lane * 4;
      const float* xb = x + (size_t)grs * HID + col;
      f32x4 o = {0, 0, 0, 0};
      #pragma unroll
      for (int i = 0; i < 8; ++i) {
        if (i < cnt_) {
          f32x4 xv = *(const f32x4*)(xb + (size_t)i * HID);
          o[0] += pbuf[i] * xv[0];
          o[1] += pbuf[i] * xv[1];
          o[2] += pbuf[i] * xv[2];
          o[3] += pbuf[i] * xv[3];
        }
      }
      for (int i = 8; i < cnt_; ++i) {   // generality tail (unused for this data)
        float p = exp2f((s_lds[lrs + i] - mmax) * LOG2E) * rden;
        f32x4 xv = *(const f32x4*)(xb + (size_t)i * HID);
        o[0] += p * xv[0];
        o[1] += p * xv[1];
        o[2] += p * xv[2];
        o[3] += p * xv[3];
      }
      *(f32x4*)(out + (size_t)gw * HID + col) = o;
    }
  }
  #undef A_ISS
  #undef A_WRT
  #undef B_ISS
  #undef B_WRT
  #undef LDA
  #undef QMM
  #undef BAR
  #undef LGKM0
}

// ==== fallback (fused 64-row kernel, fp32-B path) if workspace too small ====
__global__ __launch_bounds__(1024, 1) void fused_fb(
    const float* __restrict__ x, const float* __restrict__ Wf,
    const float* __restrict__ bias, const float* __restrict__ scw,
    const int* __restrict__ mapping, float* __restrict__ out, int num_words)
{
  __shared__ short Abuf[64 * 64];
  __shared__ float s_lds[64];
  const int tid = threadIdx.x;
  const int tile = blockIdx.x;
  const int w0 = tile * 16;
  const int wlast = min(w0 + 15, num_words - 1);
  const int r0 = mapping[2 * w0];
  const int r1 = mapping[2 * wlast + 1];
  const int nrows = min(r1 - r0, 64);
  const int srow = tid >> 4;
  const int sslot = tid & 15;
  const bool sok = srow < nrows;
  const float* xs = x + (size_t)(r0 + srow) * HID + sslot * 4;
  char* wsw = (char*)Abuf + srow * 128 + ((sslot * 8) ^ ((srow & 7) << 4));
  if (tid < 64) s_lds[tid] = 0.0f;
  const int lane = tid & 63;
  const int wave = tid >> 6;
  const int l15 = lane & 15;
  const int lk  = lane >> 4;
  const int c0  = wave * 48;
  const char* abase = (const char*)Abuf + l15 * 128;
  const int col0 = (lk * 16) ^ ((l15 & 7) << 4);
  const int col1 = col0 ^ 64;
  const float* Bf = Wf + (size_t)(c0 + l15) * HID + lk * 8;
  f32x4 acc[4][3];
  #pragma unroll
  for (int m = 0; m < 4; ++m)
    #pragma unroll
    for (int n = 0; n < 3; ++n) acc[m][n] = (f32x4){0,0,0,0};
  #pragma unroll 1
  for (int ch = 0; ch < NCH; ++ch) {
    f32x4 pfA = sok ? *(const f32x4*)(xs + ch * 64) : (f32x4){0,0,0,0};
    *(s16x4*)(wsw) = pack4(pfA);
    __syncthreads();
    #pragma unroll
    for (int kk = 0; kk < 2; ++kk) {
      const int kg = ch * 64 + kk * 32;
      s16x8 b[3];
      #pragma unroll
      for (int n = 0; n < 3; ++n) {
        f32x4 g0 = *(const f32x4*)(Bf + n * (16 * HID) + kg);
        f32x4 g1 = *(const f32x4*)(Bf + n * (16 * HID) + kg + 4);
        b[n] = pack8(g0, g1);
      }
      #pragma unroll
      for (int m = 0; m < 4; ++m) {
        s16x8 a = *(const s16x8*)(abase + m * 2048 + (kk ? col1 : col0));
        #pragma unroll
        for (int n = 0; n < 3; ++n)
          acc[m][n] = __builtin_amdgcn_mfma_f32_16x16x32_bf16(a, b[n], acc[m][n], 0,0,0);
      }
    }
    __syncthreads();
  }
  float wv[3], bv[3];
  #pragma unroll
  for (int n = 0; n < 3; ++n) {
    int col = c0 + n * 16 + l15;
    wv[n] = scw[col];
    bv[n] = bias[col];
  }
  #pragma unroll
  for (int m = 0; m < 4; ++m) {
    #pragma unroll
    for (int r = 0; r < 4; ++r) {
      float v = 0.0f;
      #pragma unroll
      for (int n = 0; n < 3; ++n)
        v += fast_tanh(acc[m][n][r] + bv[n]) * wv[n];
      v += __shfl_xor(v, 1);
      v += __shfl_xor(v, 2);
      v += __shfl_xor(v, 4);
      v += __shfl_xor(v, 8);
      if (l15 == 0) atomicAdd(&s_lds[m * 16 + lk * 4 + r], v);
    }
  }
  __syncthreads();
  const float LOG2E = 1.4426950408889634f;
  int gw = w0 + wave;
  if (wave < 16 && gw < num_words) {
    int grs = mapping[2 * gw];
    int lrs = grs - r0;
    int cnt_ = min(mapping[2 * gw + 1] - r0, nrows) - lrs;
    float mmax = -3.0e38f;
    for (int i = 0; i < cnt_; ++i) mmax = fmaxf(mmax, s_lds[lrs + i]);
    float denom = 0.0f;
    for (int i = 0; i < cnt_; ++i) denom += exp2f((s_lds[lrs + i] - mmax) * LOG2E);
    float rden = (denom > 0.0f) ? (1.0f / denom) : 0.0f;
    #pragma unroll
    for (int j = 0; j < 3; ++j) {
      int col = j * 256 + lane * 4;
      const float* xb = x + (size_t)grs * HID + col;
      f32x4 o = {0, 0, 0, 0};
      for (int i = 0; i < cnt_; ++i) {
        float p = exp2f((s_lds[lrs + i] - mmax) * LOG2E) * rden;
        f32x4 xv = *(const f32x4*)(xb + (size_t)i * HID);
        o[0] += p * xv[0]; o[1] += p * xv[1]; o[2] += p * xv[2]; o[3] += p * xv[3];
      }
      *(f32x4*)(out + (size_t)gw * HID + col) = o;
    }
  }
}

extern "C" void kernel_launch(void* const* d_in, const int* in_sizes, int n_in,
                              void* d_out, int out_size, void* d_ws, size_t ws_size,
                              hipStream_t stream) {
  const float* x    = (const float*)d_in[0];
  const float* W    = (const float*)d_in[1];
  const float* bias = (const float*)d_in[2];
  const float* scw  = (const float*)d_in[3];
  // d_in[4] (scorer bias) shifts every logit equally -> cancels in softmax
  const int* mapping = (const int*)d_in[5];
  float* out = (float*)d_out;

  int num_words = in_sizes[5] / 2;
  int n_sub = in_sizes[0] / HID;
  int ntiles = (num_words + WPB - 1) / WPB;

  size_t wb_bytes  = (size_t)HID * HID * sizeof(short);
  size_t sg_bytes  = (size_t)n_sub * sizeof(float);
  size_t cnt_bytes = (size_t)ntiles * sizeof(int);
  size_t need = wb_bytes + sg_bytes + cnt_bytes;

  char* wsb = (char*)d_ws;
  if (ws_size >= need) {
    short* Wb     = (short*)wsb;
    float* s_glob = (float*)(wsb + wb_bytes);
    int*   cntb   = (int*)(wsb + wb_bytes + sg_bytes);
    hipMemsetAsync(s_glob, 0, sg_bytes + cnt_bytes, stream);
    int n64 = (HID / 32) * (HID / 16) * 64;
    wconv_kernel<<<(n64 + 255) / 256, 256, 0, stream>>>(W, Wb, n64);
    int swz = (ntiles % 8 == 0) ? 1 : 0;
    gemm_8ph<<<ntiles * NSTRIP, 512, 0, stream>>>(
        x, Wb, bias, scw, mapping, out, num_words, s_glob, cntb, swz);
  } else {
    int nt16 = (num_words + 15) / 16;
    fused_fb<<<nt16, 1024, 0, stream>>>(x, W, bias, scw, mapping, out, num_words);
  }
}